// Round 2
// baseline (797.077 us; speedup 1.0000x reference)
//
#include <hip/hip_runtime.h>
#include <hip/hip_bf16.h>
#include <stdint.h>

#define DIM   512
#define BATCH 64
#define KENC  1024          // encoded row: [hi(512) | lo(512)]
#define BM    128
#define BN    128
#define BKT   32
#define NKT   16
#define BUFE  16384         // ushorts per LDS buffer (32 KB): 4 planes * 4096

typedef __attribute__((ext_vector_type(8))) short short8;
typedef __attribute__((ext_vector_type(4))) float floatx4;

__device__ __forceinline__ ushort f2bf(float f) {
    __hip_bfloat16 h = __float2bfloat16(f);
    return *(ushort*)&h;
}
__device__ __forceinline__ float bf2f(ushort u) {
    __hip_bfloat16 h = *(__hip_bfloat16*)&u;
    return (float)h;
}

typedef __attribute__((address_space(3))) uint32_t lds_u32;
typedef const __attribute__((address_space(1))) uint32_t glb_u32;
__device__ __forceinline__ void gload16(const ushort* g, ushort* l) {
    __builtin_amdgcn_global_load_lds((glb_u32*)g, (lds_u32*)l, 16, 0, 0);
}

#define WAITVM(N) asm volatile("s_waitcnt vmcnt(" #N ")" ::: "memory")
#define BARRIER() do { __builtin_amdgcn_s_barrier(); __builtin_amdgcn_sched_barrier(0); } while (0)

__global__ __launch_bounds__(256) void norm_partial_kernel(const float* __restrict__ x,
                                                           float* __restrict__ partial) {
    int b = blockIdx.y;
    int i = blockIdx.x;
    const float4* xv = (const float4*)(x + (size_t)b * DIM * DIM + (size_t)i * (DIM * DIM / 16));
    float s = 0.f;
    #pragma unroll
    for (int r = 0; r < 16; ++r) {
        float4 v = xv[r * 256 + threadIdx.x];
        s += v.x * v.x + v.y * v.y + v.z * v.z + v.w * v.w;
    }
    #pragma unroll
    for (int off = 32; off > 0; off >>= 1) s += __shfl_down(s, off, 64);
    __shared__ float red[4];
    int lane = threadIdx.x & 63, wid = threadIdx.x >> 6;
    if (lane == 0) red[wid] = s;
    __syncthreads();
    if (threadIdx.x == 0) partial[b * 16 + i] = red[0] + red[1] + red[2] + red[3];
}

__global__ __launch_bounds__(256) void init_kernel(const float* __restrict__ x,
                                                   const float* __restrict__ partial,
                                                   float* __restrict__ norms,
                                                   ushort* __restrict__ Yenc,
                                                   ushort* __restrict__ Tenc) {
    int b = blockIdx.y;
    float s = 0.f;
    #pragma unroll
    for (int p = 0; p < 16; ++p) s += partial[b * 16 + p];
    float nrm = sqrtf(s);
    if (blockIdx.x == 0 && threadIdx.x == 0) norms[b] = nrm;
    float inv = 1.0f / nrm;
    int idx = (blockIdx.x * 256 + threadIdx.x) * 4;
    int r = idx >> 9;
    int c = idx & 511;
    float4 v = *(const float4*)(x + (size_t)b * DIM * DIM + idx);
    float yv[4] = {v.x * inv, v.y * inv, v.z * inv, v.w * inv};
    size_t base = (size_t)b * DIM * KENC + (size_t)r * KENC;
    ushort yhi[4], ylo[4], thi[4], tlo[4];
    #pragma unroll
    for (int j = 0; j < 4; ++j) {
        float y = yv[j];
        yhi[j] = f2bf(y);
        ylo[j] = f2bf(y - bf2f(yhi[j]));
        float t = ((c + j) == r ? 1.5f : 0.0f) - 0.5f * y;
        thi[j] = f2bf(t);
        tlo[j] = f2bf(t - bf2f(thi[j]));
    }
    *(ushort4*)(Yenc + base + c)       = *(ushort4*)yhi;
    *(ushort4*)(Yenc + base + 512 + c) = *(ushort4*)ylo;
    *(ushort4*)(Tenc + base + c)       = *(ushort4*)thi;
    *(ushort4*)(Tenc + base + 512 + c) = *(ushort4*)tlo;
}

// Stage one K-tile's HI planes (Ahi, Bhi) into LDS buffer: 4 gloads/thread.
// plane layout: 128 rows * 32 elem; physical chunk pc of row r holds logical
// chunk pc ^ ((r>>1)&3). LDS dest = base + vt*16B (lane-ordered, DMA-legal).
// 256 threads cover the 512 chunk-slots per plane via vt = tid + 256*s.
__device__ __forceinline__ void stage_hi(ushort* buf, const ushort* Ag, const ushort* Bg,
                                         int k0, int tid) {
    #pragma unroll
    for (int s = 0; s < 2; ++s) {
        int vt = tid + s * 256;
        int row = vt >> 2;
        int pc  = vt & 3;
        int kc  = ((pc ^ ((row >> 1) & 3)) << 3);
        const ushort* ar = Ag + (size_t)row * KENC + k0 + kc;
        const ushort* br = Bg + (size_t)row * KENC + k0 + kc;
        gload16(ar, &buf[vt * 8]);              // Ahi
        gload16(br, &buf[8192 + vt * 8]);       // Bhi
    }
}
// LO planes (Alo, Blo): 4 gloads/thread, issued one phase later than hi.
__device__ __forceinline__ void stage_lo(ushort* buf, const ushort* Ag, const ushort* Bg,
                                         int k0, int tid) {
    #pragma unroll
    for (int s = 0; s < 2; ++s) {
        int vt = tid + s * 256;
        int row = vt >> 2;
        int pc  = vt & 3;
        int kc  = ((pc ^ ((row >> 1) & 3)) << 3);
        const ushort* ar = Ag + (size_t)row * KENC + k0 + kc;
        const ushort* br = Bg + (size_t)row * KENC + k0 + kc;
        gload16(ar + 512, &buf[4096 + vt * 8]);   // Alo
        gload16(br + 512, &buf[12288 + vt * 8]);  // Blo
    }
}

__device__ __forceinline__ void store_enc(ushort* Cenc, size_t matoff, int gr, int gc, float v) {
    ushort hi = f2bf(v);
    ushort lo = f2bf(v - bf2f(hi));
    Cenc[matoff + (size_t)gr * KENC + gc] = hi;
    Cenc[matoff + (size_t)gr * KENC + 512 + gc] = lo;
}

// 128x128 tile, 256 threads (4 waves, each a 64x64 quadrant), double-buffered LDS
// (64 KB total -> 2 blocks/CU resident: cross-block overlap hides barrier/vmcnt
// stalls of the other block). Phase-split schedule: per K-tile, 3 phases mapping
// onto the 3 split-products, each {ds_read || stage-issue} -> barrier ->
// setprio+MFMA -> barrier. vmcnt always counted (4 loads in flight across
// barriers), never a mid-loop full drain.
// Grid: 1024 blocks = 64 matrices x 16 tiles; per XCD a matrix's 16 tiles are
// consecutive -> concurrent working set ~4 matrices (8 MB) per XCD L2.
// MODE 0: T-enc = 1.5I - 0.5*C   MODE 1: C-enc   MODE 2: fp32 C*sqrt(normA)
template <int MODE>
__global__ __launch_bounds__(256, 2) void gemm_bt(const ushort* __restrict__ A,
                                                  const ushort* __restrict__ B,
                                                  ushort* __restrict__ Cenc,
                                                  float* __restrict__ Cout,
                                                  const float* __restrict__ norms) {
    __shared__ __attribute__((aligned(16))) ushort sm[2 * BUFE];  // 64 KB

    int f = blockIdx.x;           // 1024 blocks: 64 matrices x 16 tiles
    int xcd = f & 7;
    int g   = f >> 3;             // 0..127
    int b   = xcd + 8 * (g >> 4); // 8 matrices per XCD, 16 consecutive tiles each
    int t   = g & 15;
    int bm  = t >> 2;
    int bn  = t & 3;

    size_t matoff = (size_t)b * DIM * KENC;
    const ushort* Ag = A + matoff + (size_t)bm * BM * KENC;
    const ushort* Bg = B + matoff + (size_t)bn * BN * KENC;

    int tid = threadIdx.x;
    int wave = tid >> 6, lane = tid & 63;
    int lane15 = lane & 15, quad = lane >> 4;
    int wrow = (wave >> 1) * 64;    // 2 row-groups of 64
    int wcol = (wave & 1) * 64;     // 2 col-groups of 64
    int s2 = (lane15 >> 1) & 3;
    int fo = ((quad ^ s2) << 3);

    floatx4 acc[4][4];
    #pragma unroll
    for (int i = 0; i < 4; ++i)
        #pragma unroll
        for (int j = 0; j < 4; ++j)
            acc[i][j] = (floatx4){0.f, 0.f, 0.f, 0.f};

    // prologue: tile 0, hi then lo (8 loads out); wait hi (4 left in flight)
    stage_hi(sm, Ag, Bg, 0, tid);
    stage_lo(sm, Ag, Bg, 0, tid);
    WAITVM(4);
    BARRIER();

    #pragma unroll 2
    for (int kt = 0; kt < NKT; ++kt) {
        const ushort* cur = sm + (kt & 1) * BUFE;
        ushort* nxt = sm + ((kt + 1) & 1) * BUFE;
        const ushort* Ash = cur;
        const ushort* Asl = cur + 4096;
        const ushort* Bsh = cur + 8192;
        const ushort* Bsl = cur + 12288;

        short8 ab[4], bb[4], xl[4];

        // ---- Phase 1: read hi fragments; prefetch next tile hi planes ----
        #pragma unroll
        for (int i = 0; i < 4; ++i)
            ab[i] = *(const short8*)&Ash[(wrow + i * 16 + lane15) * BKT + fo];
        #pragma unroll
        for (int j = 0; j < 4; ++j)
            bb[j] = *(const short8*)&Bsh[(wcol + j * 16 + lane15) * BKT + fo];
        if (kt + 1 < NKT) {
            stage_hi(nxt, Ag, Bg, (kt + 1) * BKT, tid);  // out: cur-lo(4) + nxt-hi(4)
            WAITVM(4);                                    // cur-lo landed; nxt-hi in flight
        } else {
            WAITVM(0);                                    // tail: drain cur-lo
        }
        BARRIER();                                        // cross-wave: all lo planes ready
        __builtin_amdgcn_s_setprio(1);
        #pragma unroll
        for (int i = 0; i < 4; ++i)
            #pragma unroll
            for (int j = 0; j < 4; ++j)
                acc[i][j] = __builtin_amdgcn_mfma_f32_16x16x32_bf16(ab[i], bb[j], acc[i][j], 0, 0, 0);
        __builtin_amdgcn_s_setprio(0);
        BARRIER();

        // ---- Phase 2: read Blo; prefetch next tile lo planes ----
        #pragma unroll
        for (int j = 0; j < 4; ++j)
            xl[j] = *(const short8*)&Bsl[(wcol + j * 16 + lane15) * BKT + fo];
        if (kt + 1 < NKT)
            stage_lo(nxt, Ag, Bg, (kt + 1) * BKT, tid);   // out: nxt-hi(4) + nxt-lo(4)
        BARRIER();
        __builtin_amdgcn_s_setprio(1);
        #pragma unroll
        for (int i = 0; i < 4; ++i)
            #pragma unroll
            for (int j = 0; j < 4; ++j)
                acc[i][j] = __builtin_amdgcn_mfma_f32_16x16x32_bf16(ab[i], xl[j], acc[i][j], 0, 0, 0);
        __builtin_amdgcn_s_setprio(0);
        BARRIER();

        // ---- Phase 3: read Alo (reuse ab registers) ----
        #pragma unroll
        for (int i = 0; i < 4; ++i)
            ab[i] = *(const short8*)&Asl[(wrow + i * 16 + lane15) * BKT + fo];
        BARRIER();
        __builtin_amdgcn_s_setprio(1);
        #pragma unroll
        for (int i = 0; i < 4; ++i)
            #pragma unroll
            for (int j = 0; j < 4; ++j)
                acc[i][j] = __builtin_amdgcn_mfma_f32_16x16x32_bf16(ab[i], bb[j], acc[i][j], 0, 0, 0);
        __builtin_amdgcn_s_setprio(0);
        // tile boundary: wait next tile's hi planes (lo stay in flight)
        if (kt + 1 < NKT) WAITVM(4);
        BARRIER();
    }

    float scale = (MODE == 2) ? sqrtf(norms[b]) : 0.f;
    #pragma unroll
    for (int i = 0; i < 4; ++i) {
        int gr0 = bm * BM + wrow + i * 16 + quad * 4;
        #pragma unroll
        for (int j = 0; j < 4; ++j) {
            int gc = bn * BN + wcol + j * 16 + lane15;
            #pragma unroll
            for (int rr = 0; rr < 4; ++rr) {
                int gr = gr0 + rr;
                float cv = acc[i][j][rr];
                if (MODE == 0) {
                    store_enc(Cenc, matoff, gr, gc, (gr == gc ? 1.5f : 0.0f) - 0.5f * cv);
                } else if (MODE == 1) {
                    store_enc(Cenc, matoff, gr, gc, cv);
                } else {
                    Cout[(size_t)b * DIM * DIM + (size_t)gr * DIM + gc] = cv * scale;
                }
            }
        }
    }
}

extern "C" void kernel_launch(void* const* d_in, const int* in_sizes, int n_in,
                              void* d_out, int out_size, void* d_ws, size_t ws_size,
                              hipStream_t stream) {
    const float* x = (const float*)d_in[0];  // d_in[1] = I, unused
    float* out = (float*)d_out;

    const size_t MATB = (size_t)BATCH * DIM * KENC * sizeof(ushort);  // 64 MB
    char* ws = (char*)d_ws;
    ushort* W0 = (ushort*)(ws + 0 * MATB);
    ushort* W1 = (ushort*)(ws + 1 * MATB);
    ushort* W2 = (ushort*)(ws + 2 * MATB);
    float* partial = (float*)(ws + 3 * MATB);          // 192 MB + 4 KB total
    float* norms   = (float*)(ws + 3 * MATB + 4096);
    ushort* D = (ushort*)d_out;  // encoded scratch slot #4; final fp32 GEMM overwrites last

    dim3 gblk(256);
    dim3 g1(1024);

    norm_partial_kernel<<<dim3(16, BATCH), 256, 0, stream>>>(x, partial);
    init_kernel<<<dim3(256, BATCH), 256, 0, stream>>>(x, partial, norms, W0, W1);  // Y0->W0, T1(=Z1)->W1

    // iter 1: Y1 = Y0*T1 -> W2 ; Z1 = T1 (W1).             live: Y1=W2, Z1=W1   free: W0, D
    gemm_bt<1><<<g1, gblk, 0, stream>>>(W0, W1, W2, nullptr, nullptr);
    // iter 2: T2 = f(Z1*Y1) -> W0                          live: Y1=W2, Z1=W1, T2=W0   free: D
    gemm_bt<0><<<g1, gblk, 0, stream>>>(W1, W2, W0, nullptr, nullptr);
    gemm_bt<1><<<g1, gblk, 0, stream>>>(W2, W0, D, nullptr, nullptr);   // Y2 -> D
    gemm_bt<1><<<g1, gblk, 0, stream>>>(W0, W1, W2, nullptr, nullptr);  // Z2 = T2*Z1 -> W2
    // iter 3
    gemm_bt<0><<<g1, gblk, 0, stream>>>(W2, D, W0, nullptr, nullptr);   // T3 -> W0
    gemm_bt<1><<<g1, gblk, 0, stream>>>(D, W0, W1, nullptr, nullptr);   // Y3 -> W1
    gemm_bt<1><<<g1, gblk, 0, stream>>>(W0, W2, D, nullptr, nullptr);   // Z3 = T3*Z2 -> D
    // iter 4
    gemm_bt<0><<<g1, gblk, 0, stream>>>(D, W1, W0, nullptr, nullptr);   // T4 -> W0
    gemm_bt<1><<<g1, gblk, 0, stream>>>(W1, W0, W2, nullptr, nullptr);  // Y4 -> W2
    gemm_bt<1><<<g1, gblk, 0, stream>>>(W0, D, W1, nullptr, nullptr);   // Z4 = T4*Z3 -> W1
    // iter 5
    gemm_bt<0><<<g1, gblk, 0, stream>>>(W1, W2, W0, nullptr, nullptr);  // T5 -> W0
    gemm_bt<2><<<g1, gblk, 0, stream>>>(W2, W0, nullptr, out, norms);   // out = Y4*T5*sqrt(n)
}

// Round 3
// 715.799 us; speedup vs baseline: 1.1135x; 1.1135x over previous
//
#include <hip/hip_runtime.h>
#include <hip/hip_bf16.h>
#include <stdint.h>

#define DIM   512
#define BATCH 64
#define KENC  1024          // encoded row: [hi(512) | lo(512)]
#define BM    256
#define BN    256
#define BKT   32
#define NKT   16
#define BUFE  32768         // ushorts per LDS buffer (64 KB): 4 planes * 8192

typedef __attribute__((ext_vector_type(8))) short short8;
typedef __attribute__((ext_vector_type(4))) float floatx4;

__device__ __forceinline__ ushort f2bf(float f) {
    __hip_bfloat16 h = __float2bfloat16(f);
    return *(ushort*)&h;
}
__device__ __forceinline__ float bf2f(ushort u) {
    __hip_bfloat16 h = *(__hip_bfloat16*)&u;
    return (float)h;
}

typedef __attribute__((address_space(3))) uint32_t lds_u32;
typedef const __attribute__((address_space(1))) uint32_t glb_u32;
__device__ __forceinline__ void gload16(const ushort* g, ushort* l) {
    __builtin_amdgcn_global_load_lds((glb_u32*)g, (lds_u32*)l, 16, 0, 0);
}

#define WAITVM(N) asm volatile("s_waitcnt vmcnt(" #N ")" ::: "memory")
#define BARRIER() do { __builtin_amdgcn_s_barrier(); __builtin_amdgcn_sched_barrier(0); } while (0)
#define SCHED()   __builtin_amdgcn_sched_barrier(0)

__global__ __launch_bounds__(256) void norm_partial_kernel(const float* __restrict__ x,
                                                           float* __restrict__ partial) {
    int b = blockIdx.y;
    int i = blockIdx.x;
    const float4* xv = (const float4*)(x + (size_t)b * DIM * DIM + (size_t)i * (DIM * DIM / 16));
    float s = 0.f;
    #pragma unroll
    for (int r = 0; r < 16; ++r) {
        float4 v = xv[r * 256 + threadIdx.x];
        s += v.x * v.x + v.y * v.y + v.z * v.z + v.w * v.w;
    }
    #pragma unroll
    for (int off = 32; off > 0; off >>= 1) s += __shfl_down(s, off, 64);
    __shared__ float red[4];
    int lane = threadIdx.x & 63, wid = threadIdx.x >> 6;
    if (lane == 0) red[wid] = s;
    __syncthreads();
    if (threadIdx.x == 0) partial[b * 16 + i] = red[0] + red[1] + red[2] + red[3];
}

__global__ __launch_bounds__(256) void init_kernel(const float* __restrict__ x,
                                                   const float* __restrict__ partial,
                                                   float* __restrict__ norms,
                                                   ushort* __restrict__ Yenc,
                                                   ushort* __restrict__ Tenc) {
    int b = blockIdx.y;
    float s = 0.f;
    #pragma unroll
    for (int p = 0; p < 16; ++p) s += partial[b * 16 + p];
    float nrm = sqrtf(s);
    if (blockIdx.x == 0 && threadIdx.x == 0) norms[b] = nrm;
    float inv = 1.0f / nrm;
    int idx = (blockIdx.x * 256 + threadIdx.x) * 4;
    int r = idx >> 9;
    int c = idx & 511;
    float4 v = *(const float4*)(x + (size_t)b * DIM * DIM + idx);
    float yv[4] = {v.x * inv, v.y * inv, v.z * inv, v.w * inv};
    size_t base = (size_t)b * DIM * KENC + (size_t)r * KENC;
    ushort yhi[4], ylo[4], thi[4], tlo[4];
    #pragma unroll
    for (int j = 0; j < 4; ++j) {
        float y = yv[j];
        yhi[j] = f2bf(y);
        ylo[j] = f2bf(y - bf2f(yhi[j]));
        float t = ((c + j) == r ? 1.5f : 0.0f) - 0.5f * y;
        thi[j] = f2bf(t);
        tlo[j] = f2bf(t - bf2f(thi[j]));
    }
    *(ushort4*)(Yenc + base + c)       = *(ushort4*)yhi;
    *(ushort4*)(Yenc + base + 512 + c) = *(ushort4*)ylo;
    *(ushort4*)(Tenc + base + c)       = *(ushort4*)thi;
    *(ushort4*)(Tenc + base + 512 + c) = *(ushort4*)tlo;
}

// Stage one K-tile's HI unit (Ahi plane @0, Bhi plane @16384): 4 gloads/thread.
// plane layout: 256 rows * 32 elem; physical chunk pc of row r holds logical
// chunk pc ^ ((r>>1)&3). LDS dest = base + vt*16B (lane-ordered, DMA-legal).
__device__ __forceinline__ void stage_hi(ushort* buf, const ushort* Ag, const ushort* Bg,
                                         int k0, int tid) {
    #pragma unroll
    for (int s = 0; s < 2; ++s) {
        int vt = tid + s * 512;
        int row = vt >> 2;
        int pc  = vt & 3;
        int kc  = ((pc ^ ((row >> 1) & 3)) << 3);
        const ushort* ar = Ag + (size_t)row * KENC + k0 + kc;
        const ushort* br = Bg + (size_t)row * KENC + k0 + kc;
        gload16(ar, &buf[vt * 8]);              // Ahi
        gload16(br, &buf[16384 + vt * 8]);      // Bhi
    }
}
// LO unit (Alo @8192, Blo @24576): 4 gloads/thread, issued one barrier-region later.
__device__ __forceinline__ void stage_lo(ushort* buf, const ushort* Ag, const ushort* Bg,
                                         int k0, int tid) {
    #pragma unroll
    for (int s = 0; s < 2; ++s) {
        int vt = tid + s * 512;
        int row = vt >> 2;
        int pc  = vt & 3;
        int kc  = ((pc ^ ((row >> 1) & 3)) << 3);
        const ushort* ar = Ag + (size_t)row * KENC + k0 + kc;
        const ushort* br = Bg + (size_t)row * KENC + k0 + kc;
        gload16(ar + 512, &buf[8192 + vt * 8]);   // Alo
        gload16(br + 512, &buf[24576 + vt * 8]);  // Blo
    }
}

__device__ __forceinline__ void store_enc(ushort* Cenc, size_t matoff, int gr, int gc, float v) {
    ushort hi = f2bf(v);
    ushort lo = f2bf(v - bf2f(hi));
    Cenc[matoff + (size_t)gr * KENC + gc] = hi;
    Cenc[matoff + (size_t)gr * KENC + 512 + gc] = lo;
}

// 256x256 tile, 512 threads (8 waves, each a 128x64 sub-tile), double-buffered LDS.
// Minimal-barrier schedule: only 2 runtime barriers per K-tile (after the counted
// vmcnt waits for the hi-unit and lo-unit stages). All other ordering is per-wave:
// 6 fine compute phases of 16 MFMA each, pinned with sched_barrier(0). Without
// mid-tile barriers, waves skew freely, so one wave's ds_read bursts overlap
// another wave's MFMA clusters (intra-block wave-level overlap).
// Hazards: stage->read covered by {per-wave vmcnt(4) + barrier}; read->overwrite
// covered because each ds_read is drained by its consuming MFMA (compiler lgkmcnt)
// before the wave reaches the next barrier, and the overwriting stage for that
// slot is issued >=1 full barrier later.
// MODE 0: T-enc = 1.5I - 0.5*C   MODE 1: C-enc   MODE 2: fp32 C*sqrt(normA)
template <int MODE>
__global__ __launch_bounds__(512, 2) void gemm_bt(const ushort* __restrict__ A,
                                                  const ushort* __restrict__ B,
                                                  ushort* __restrict__ Cenc,
                                                  float* __restrict__ Cout,
                                                  const float* __restrict__ norms) {
    __shared__ __attribute__((aligned(16))) ushort sm[2 * BUFE];  // 128 KB

    int f = blockIdx.x;           // 256 blocks: 64 matrices x 4 quadrant-tiles
    int xcd = f & 7;
    int g   = f >> 3;             // 0..31
    int b   = xcd + 8 * (g >> 2); // 8 matrices per XCD (4 co-tiles each)
    int t   = g & 3;
    int bm  = t >> 1;
    int bn  = t & 1;

    size_t matoff = (size_t)b * DIM * KENC;
    const ushort* Ag = A + matoff + (size_t)bm * BM * KENC;
    const ushort* Bg = B + matoff + (size_t)bn * BN * KENC;

    int tid = threadIdx.x;
    int wave = tid >> 6, lane = tid & 63;
    int lane15 = lane & 15, quad = lane >> 4;
    int wrow = (wave >> 2) * 128;   // 2 row-groups of 128
    int wcol = (wave & 3) * 64;     // 4 col-groups of 64
    int s2 = (lane15 >> 1) & 3;
    int fo = ((quad ^ s2) << 3);

    floatx4 acc[8][4];
    #pragma unroll
    for (int i = 0; i < 8; ++i)
        #pragma unroll
        for (int j = 0; j < 4; ++j)
            acc[i][j] = (floatx4){0.f, 0.f, 0.f, 0.f};

    // prologue: tile 0 hi unit (4 loads) then lo unit (4 loads); 8 in flight
    stage_hi(sm, Ag, Bg, 0, tid);
    stage_lo(sm, Ag, Bg, 0, tid);

    #pragma unroll 2
    for (int kt = 0; kt < NKT; ++kt) {
        const ushort* cur = sm + (kt & 1) * BUFE;
        ushort* nxt = sm + ((kt + 1) & 1) * BUFE;
        const ushort* Ash = cur;
        const ushort* Asl = cur + 8192;
        const ushort* Bsh = cur + 16384;
        const ushort* Bsl = cur + 24576;

        short8 ah[8], bh[4], bl[4], al[4];

        // ==== barrier region 1: hi unit of tile kt ready ====
        WAITVM(4);          // outstanding after hi(kt): lo(kt) = 4  -> hi(kt) landed
        BARRIER();          // all waves' hi-unit portions landed

        // -- Phase 1: read A-hi rows 0..3 + B-hi; stage next hi unit; MFMA hi.hi (top) --
        #pragma unroll
        for (int i = 0; i < 4; ++i)
            ah[i] = *(const short8*)&Ash[(wrow + i * 16 + lane15) * BKT + fo];
        #pragma unroll
        for (int j = 0; j < 4; ++j)
            bh[j] = *(const short8*)&Bsh[(wcol + j * 16 + lane15) * BKT + fo];
        if (kt + 1 < NKT) stage_hi(nxt, Ag, Bg, (kt + 1) * BKT, tid);
        __builtin_amdgcn_s_setprio(1);
        #pragma unroll
        for (int i = 0; i < 4; ++i)
            #pragma unroll
            for (int j = 0; j < 4; ++j)
                acc[i][j] = __builtin_amdgcn_mfma_f32_16x16x32_bf16(ah[i], bh[j], acc[i][j], 0, 0, 0);
        __builtin_amdgcn_s_setprio(0);
        SCHED();

        // -- Phase 2: read A-hi rows 4..7; MFMA hi.hi (bottom) --
        #pragma unroll
        for (int i = 4; i < 8; ++i)
            ah[i] = *(const short8*)&Ash[(wrow + i * 16 + lane15) * BKT + fo];
        __builtin_amdgcn_s_setprio(1);
        #pragma unroll
        for (int i = 4; i < 8; ++i)
            #pragma unroll
            for (int j = 0; j < 4; ++j)
                acc[i][j] = __builtin_amdgcn_mfma_f32_16x16x32_bf16(ah[i], bh[j], acc[i][j], 0, 0, 0);
        __builtin_amdgcn_s_setprio(0);
        SCHED();

        // ==== barrier region 2: lo unit of tile kt ready ====
        if (kt + 1 < NKT) { WAITVM(4); }   // outstanding after lo(kt): hi(kt+1) = 4
        else             { WAITVM(0); }    // tail: nothing staged after lo(kt)
        BARRIER();

        // -- Phase 3: read B-lo; stage next lo unit; MFMA hi.lo (top) --
        #pragma unroll
        for (int j = 0; j < 4; ++j)
            bl[j] = *(const short8*)&Bsl[(wcol + j * 16 + lane15) * BKT + fo];
        if (kt + 1 < NKT) stage_lo(nxt, Ag, Bg, (kt + 1) * BKT, tid);
        __builtin_amdgcn_s_setprio(1);
        #pragma unroll
        for (int i = 0; i < 4; ++i)
            #pragma unroll
            for (int j = 0; j < 4; ++j)
                acc[i][j] = __builtin_amdgcn_mfma_f32_16x16x32_bf16(ah[i], bl[j], acc[i][j], 0, 0, 0);
        __builtin_amdgcn_s_setprio(0);
        SCHED();

        // -- Phase 4: MFMA hi.lo (bottom) --
        __builtin_amdgcn_s_setprio(1);
        #pragma unroll
        for (int i = 4; i < 8; ++i)
            #pragma unroll
            for (int j = 0; j < 4; ++j)
                acc[i][j] = __builtin_amdgcn_mfma_f32_16x16x32_bf16(ah[i], bl[j], acc[i][j], 0, 0, 0);
        __builtin_amdgcn_s_setprio(0);
        SCHED();

        // -- Phase 5: read A-lo rows 0..3; MFMA lo.hi (top) --
        #pragma unroll
        for (int i = 0; i < 4; ++i)
            al[i] = *(const short8*)&Asl[(wrow + i * 16 + lane15) * BKT + fo];
        __builtin_amdgcn_s_setprio(1);
        #pragma unroll
        for (int i = 0; i < 4; ++i)
            #pragma unroll
            for (int j = 0; j < 4; ++j)
                acc[i][j] = __builtin_amdgcn_mfma_f32_16x16x32_bf16(al[i], bh[j], acc[i][j], 0, 0, 0);
        __builtin_amdgcn_s_setprio(0);
        SCHED();

        // -- Phase 6: read A-lo rows 4..7; MFMA lo.hi (bottom) --
        #pragma unroll
        for (int i = 0; i < 4; ++i)
            al[i] = *(const short8*)&Asl[(wrow + (i + 4) * 16 + lane15) * BKT + fo];
        __builtin_amdgcn_s_setprio(1);
        #pragma unroll
        for (int i = 0; i < 4; ++i)
            #pragma unroll
            for (int j = 0; j < 4; ++j)
                acc[i + 4][j] = __builtin_amdgcn_mfma_f32_16x16x32_bf16(al[i], bh[j], acc[i + 4][j], 0, 0, 0);
        __builtin_amdgcn_s_setprio(0);
        SCHED();
    }

    float scale = (MODE == 2) ? sqrtf(norms[b]) : 0.f;
    #pragma unroll
    for (int i = 0; i < 8; ++i) {
        int gr0 = bm * BM + wrow + i * 16 + quad * 4;
        #pragma unroll
        for (int j = 0; j < 4; ++j) {
            int gc = bn * BN + wcol + j * 16 + lane15;
            #pragma unroll
            for (int rr = 0; rr < 4; ++rr) {
                int gr = gr0 + rr;
                float cv = acc[i][j][rr];
                if (MODE == 0) {
                    store_enc(Cenc, matoff, gr, gc, (gr == gc ? 1.5f : 0.0f) - 0.5f * cv);
                } else if (MODE == 1) {
                    store_enc(Cenc, matoff, gr, gc, cv);
                } else {
                    Cout[(size_t)b * DIM * DIM + (size_t)gr * DIM + gc] = cv * scale;
                }
            }
        }
    }
}

extern "C" void kernel_launch(void* const* d_in, const int* in_sizes, int n_in,
                              void* d_out, int out_size, void* d_ws, size_t ws_size,
                              hipStream_t stream) {
    const float* x = (const float*)d_in[0];  // d_in[1] = I, unused
    float* out = (float*)d_out;

    const size_t MATB = (size_t)BATCH * DIM * KENC * sizeof(ushort);  // 64 MB
    char* ws = (char*)d_ws;
    ushort* W0 = (ushort*)(ws + 0 * MATB);
    ushort* W1 = (ushort*)(ws + 1 * MATB);
    ushort* W2 = (ushort*)(ws + 2 * MATB);
    float* partial = (float*)(ws + 3 * MATB);          // 192 MB + 4 KB total
    float* norms   = (float*)(ws + 3 * MATB + 4096);
    ushort* D = (ushort*)d_out;  // encoded scratch slot #4; final fp32 GEMM overwrites last

    dim3 gblk(512);
    dim3 g1(256);

    norm_partial_kernel<<<dim3(16, BATCH), 256, 0, stream>>>(x, partial);
    init_kernel<<<dim3(256, BATCH), 256, 0, stream>>>(x, partial, norms, W0, W1);  // Y0->W0, T1(=Z1)->W1

    // iter 1: Y1 = Y0*T1 -> W2 ; Z1 = T1 (W1).             live: Y1=W2, Z1=W1   free: W0, D
    gemm_bt<1><<<g1, gblk, 0, stream>>>(W0, W1, W2, nullptr, nullptr);
    // iter 2: T2 = f(Z1*Y1) -> W0                          live: Y1=W2, Z1=W1, T2=W0   free: D
    gemm_bt<0><<<g1, gblk, 0, stream>>>(W1, W2, W0, nullptr, nullptr);
    gemm_bt<1><<<g1, gblk, 0, stream>>>(W2, W0, D, nullptr, nullptr);   // Y2 -> D
    gemm_bt<1><<<g1, gblk, 0, stream>>>(W0, W1, W2, nullptr, nullptr);  // Z2 = T2*Z1 -> W2
    // iter 3
    gemm_bt<0><<<g1, gblk, 0, stream>>>(W2, D, W0, nullptr, nullptr);   // T3 -> W0
    gemm_bt<1><<<g1, gblk, 0, stream>>>(D, W0, W1, nullptr, nullptr);   // Y3 -> W1
    gemm_bt<1><<<g1, gblk, 0, stream>>>(W0, W2, D, nullptr, nullptr);   // Z3 = T3*Z2 -> D
    // iter 4
    gemm_bt<0><<<g1, gblk, 0, stream>>>(D, W1, W0, nullptr, nullptr);   // T4 -> W0
    gemm_bt<1><<<g1, gblk, 0, stream>>>(W1, W0, W2, nullptr, nullptr);  // Y4 -> W2
    gemm_bt<1><<<g1, gblk, 0, stream>>>(W0, D, W1, nullptr, nullptr);   // Z4 = T4*Z3 -> W1
    // iter 5
    gemm_bt<0><<<g1, gblk, 0, stream>>>(W1, W2, W0, nullptr, nullptr);  // T5 -> W0
    gemm_bt<2><<<g1, gblk, 0, stream>>>(W2, W0, nullptr, out, norms);   // out = Y4*T5*sqrt(n)
}